// Round 14
// baseline (290.819 us; speedup 1.0000x reference)
//
#include <hip/hip_runtime.h>

// GCNConv: out = D^-1/2 (A+I) D^-1/2 X W + b
// N=100000, E=1600000, Din=Dout=128; x/W/b fp32, edge_index int32, out fp32.
//
// R18 = R17 (248.9us; gather 65.5us via dis-fold) with the ENTIRE first
// sort level deleted:
//   - srw becomes NC bucket-regions of CAP=3072 int2; k_place allocates
//     each bucket's global base with ONE atomicAdd(&gcur[b], count) per
//     (block,bucket) (~560K coarse atomics total; R10's poison was 3.2M
//     per-edge returning atomics). LDS staging identical to R12-R17.
//   - k_bscan (1 block) scans the 782 final counts -> bstart (CSR base).
//   - DELETED: k_hist (611K-cell histg + 2.4MB scatter), k_scan1 (4.8MB),
//     k_scan2, 2-3 launch boundaries. W-prep folds into place blocks 0-63.
//   Pipeline: memset(3KB) -> place(+wprep) -> bscan -> fine -> gemm -> gather.
//   gemm (dis-scaled h') and gather are byte-identical to R17.

#define CHUNK 2048                 // edges per place block
#define NCMAX 800                  // >= NC = ceil(N/128) = 782
#define CAP 3072                   // bucket region capacity (mean 2046, sd 45)

typedef __attribute__((ext_vector_type(8))) short short8;
typedef __attribute__((ext_vector_type(4))) float f32x4;

__device__ inline unsigned short f2bf(float f) {  // fp32 -> bf16 RNE
    unsigned u = __float_as_uint(f);
    u += 0x7fffu + ((u >> 16) & 1u);
    return (unsigned short)(u >> 16);
}
__device__ inline float bf_lo(unsigned u) { return __uint_as_float(u << 16); }
__device__ inline float bf_hi(unsigned u) { return __uint_as_float(u & 0xffff0000u); }

__device__ inline int wave_incl_scan(int x, int lane) {
    #pragma unroll
    for (int d = 1; d < 64; d <<= 1) {
        int y = __shfl_up(x, d, 64);
        if (lane >= d) x += y;
    }
    return x;
}

// ---- place: LDS-staged bucket sort with atomic region allocation ----
__global__ __launch_bounds__(256) void k_place(const int* __restrict__ row,
                                               const int* __restrict__ col,
                                               const float* __restrict__ wgt,
                                               const float* __restrict__ W,
                                               unsigned short* __restrict__ Wtg,
                                               int* __restrict__ gcur,
                                               int2* __restrict__ srw,
                                               int E, int NC) {
    __shared__ struct { int lcnt[NCMAX]; int gadj[NCMAX]; int2 stage[CHUNK];
                        int sdst[CHUNK]; int wsum[4]; int woff[4]; } sp;  // 30.0 KB
    int t = threadIdx.x, blk = blockIdx.x;
    int lane = t & 63, wid = t >> 6;
    if (blk < 64) {  // W transpose+bf16 fold: 2 rows per block
        int n = blk * 2 + (t >> 7);
        int k = t & 127;
        Wtg[n * 128 + k] = f2bf(W[k * 128 + n]);
    }
    int base = blk * CHUNK;
    int nE = min(CHUNK, E - base);
    for (int b = t; b < NCMAX; b += 256) sp.lcnt[b] = 0;
    __syncthreads();
    // pass A: local count
    #pragma unroll
    for (int i = 0; i < CHUNK / 256; ++i) {
        int e = base + i * 256 + t;
        if (e < E) atomicAdd(&sp.lcnt[col[e] >> 7], 1);
    }
    __syncthreads();
    // block-wide exclusive scan of lcnt[0..NCMAX), 4 entries/thread
    int c4[4], cv[4];
    int sum = 0;
    #pragma unroll
    for (int i = 0; i < 4; ++i) {
        int idx = t * 4 + i;
        int v = (idx < NCMAX) ? sp.lcnt[idx] : 0;
        cv[i] = v;
        c4[i] = sum; sum += v;
    }
    int incl = wave_incl_scan(sum, lane);
    int excl = incl - sum;
    if (lane == 63) sp.wsum[wid] = incl;
    __syncthreads();
    if (t == 0) {
        int r = 0;
        #pragma unroll
        for (int w = 0; w < 4; ++w) { int s = sp.wsum[w]; sp.woff[w] = r; r += s; }
    }
    __syncthreads();
    int tb = sp.woff[wid] + excl;
    __syncthreads();
    // allocate global region space per bucket; rewrite lcnt as local cursors
    #pragma unroll
    for (int i = 0; i < 4; ++i) {
        int idx = t * 4 + i;
        if (idx < NCMAX) {
            int b0 = tb + c4[i];
            int gb = 0;
            if (idx < NC && cv[i] > 0) gb = atomicAdd(&gcur[idx], cv[i]);
            sp.gadj[idx] = idx * CAP + gb - b0;
            sp.lcnt[idx] = b0;
        }
    }
    __syncthreads();
    // pass B: scatter into LDS by bucket
    #pragma unroll
    for (int i = 0; i < CHUNK / 256; ++i) {
        int e = base + i * 256 + t;
        if (e < E) {
            int c = col[e];
            int slot = atomicAdd(&sp.lcnt[c >> 7], 1);
            sp.stage[slot] = make_int2(((c & 127) << 17) | row[e], __float_as_int(wgt[e]));
            sp.sdst[slot] = sp.gadj[c >> 7] + slot;
        }
    }
    __syncthreads();
    // output: consecutive slots -> mostly-consecutive region addresses
    int lim = NC * CAP;
    for (int s_ = t; s_ < nE; s_ += 256) {
        int d = sp.sdst[s_];
        if (d < lim) srw[d] = sp.stage[s_];   // bound guard (adversarial overflow)
    }
}

// ---- bscan: 1 block; exclusive scan of gcur[0..NC) -> bstart ----
__global__ void k_bscan(const int* __restrict__ gcur, int* __restrict__ bstart, int NC) {
    __shared__ int wsum[4];
    __shared__ int woff[4];
    int t = threadIdx.x, lane = t & 63, wid = t >> 6;
    int c4[4];
    int sum = 0;
    #pragma unroll
    for (int i = 0; i < 4; ++i) {
        int idx = t * 4 + i;
        int v = (idx < NC) ? gcur[idx] : 0;
        c4[i] = sum; sum += v;
    }
    int incl = wave_incl_scan(sum, lane);
    int excl = incl - sum;
    if (lane == 63) wsum[wid] = incl;
    __syncthreads();
    if (t == 0) {
        int r = 0;
        #pragma unroll
        for (int w = 0; w < 4; ++w) { int s = wsum[w]; woff[w] = r; r += s; }
    }
    __syncthreads();
    int tb = woff[wid] + excl;
    #pragma unroll
    for (int i = 0; i < 4; ++i) {
        int idx = t * 4 + i;
        if (idx < NC) bstart[idx] = tb + c4[i];
    }
}

// ---- fine: exact CSR within each 128-node bucket + dis + spack ----
__global__ __launch_bounds__(256) void k_fine(const int* __restrict__ gcur,
                                              const int* __restrict__ bstart,
                                              const int2* __restrict__ srw,
                                              int* __restrict__ rowptr,
                                              float* __restrict__ dis,
                                              int2* __restrict__ spack,
                                              int E, int N, int NC) {
    __shared__ struct { int2 sbuf[3072]; int cnt128[128]; float degf[128];
                        int cur128[128]; int wtot[2]; } sf;   // 25.7 KB
    int t = threadIdx.x, b = blockIdx.x;
    int nb = b << 7;
    int cnt = gcur[b];
    if (cnt > CAP) cnt = CAP;
    int in_base = b * CAP;
    int out_base = bstart[b];
    int NL = min(cnt, 3072);
    if (t < 128) { sf.cnt128[t] = 0; sf.degf[t] = 1.0f; }  // 1.0 = self-loop
    __syncthreads();
    // phase 1: single region read; stage into LDS
    for (int j = t; j < cnt; j += 256) {
        int2 s = srw[in_base + j];
        if (j < NL) sf.sbuf[j] = s;
        int c = s.x >> 17;
        atomicAdd(&sf.cnt128[c], 1);
        atomicAdd(&sf.degf[c], __int_as_float(s.y));
    }
    __syncthreads();
    // phase 2: 128-entry exclusive scan, write rowptr/dis, seed cursors
    int v = 0, incl = 0;
    if (t < 128) {
        v = sf.cnt128[t];
        incl = wave_incl_scan(v, t & 63);
        if ((t & 63) == 63) sf.wtot[t >> 6] = incl;
    }
    __syncthreads();
    if (t < 128) {
        int excl = incl - v + ((t >= 64) ? sf.wtot[0] : 0);
        int p = out_base + excl;
        sf.cur128[t] = p;
        int n = nb + t;
        if (n < N) {
            rowptr[n] = p;
            dis[n] = rsqrtf(sf.degf[t]);
        }
    }
    if (t == 0 && b == NC - 1) rowptr[N] = out_base + cnt;
    __syncthreads();
    // phase 3: final placement from LDS
    for (int j = t; j < cnt; j += 256) {
        int2 s = (j < NL) ? sf.sbuf[j] : srw[in_base + j];
        int c = s.x >> 17;
        int pos = atomicAdd(&sf.cur128[c], 1);
        spack[pos] = make_int2(s.x & 0x1FFFF, s.y);
    }
}

// ---- gemm: h' = (x @ W) scaled by dis (runs AFTER fine) ----
__global__ __launch_bounds__(256) void k_gemm(const float* __restrict__ x,
                                              const unsigned short* __restrict__ Wtg,
                                              const float* __restrict__ dis,
                                              unsigned short* __restrict__ h, int N) {
    __shared__ struct { short Xs[64][72]; short Ws[128][72]; } sm;  // 27.6 KB
    int t = threadIdx.x;
    int lane = t & 63, wid = t >> 6;
    int row0 = blockIdx.x * 64;
    int q = lane >> 4;
    int m = lane & 15;
    f32x4 acc[8];
    #pragma unroll
    for (int tde = 0; tde < 8; ++tde) acc[tde] = (f32x4){0.f, 0.f, 0.f, 0.f};

    #pragma unroll
    for (int kh = 0; kh < 2; ++kh) {
        {   // X half: 64 rows x 64 K; 16 floats/thread
            int r = t >> 2;
            int kf = (t & 3) * 16;
            int gr = row0 + r;
            const float4* src = (const float4*)(x + (size_t)gr * 128 + kh * 64 + kf);
            float4 a0 = make_float4(0.f, 0.f, 0.f, 0.f), a1 = a0, a2 = a0, a3 = a0;
            if (gr < N) { a0 = src[0]; a1 = src[1]; a2 = src[2]; a3 = src[3]; }
            short8 p0, p1;
            p0[0] = (short)f2bf(a0.x); p0[1] = (short)f2bf(a0.y);
            p0[2] = (short)f2bf(a0.z); p0[3] = (short)f2bf(a0.w);
            p0[4] = (short)f2bf(a1.x); p0[5] = (short)f2bf(a1.y);
            p0[6] = (short)f2bf(a1.z); p0[7] = (short)f2bf(a1.w);
            p1[0] = (short)f2bf(a2.x); p1[1] = (short)f2bf(a2.y);
            p1[2] = (short)f2bf(a2.z); p1[3] = (short)f2bf(a2.w);
            p1[4] = (short)f2bf(a3.x); p1[5] = (short)f2bf(a3.y);
            p1[6] = (short)f2bf(a3.z); p1[7] = (short)f2bf(a3.w);
            *(short8*)&sm.Xs[r][kf]     = p0;
            *(short8*)&sm.Xs[r][kf + 8] = p1;
        }
        {   // W half: 128 rows x 64 K; 32 shorts/thread
            int n = t >> 1;
            int off = (t & 1) * 32;
            const short* wsrc = (const short*)Wtg + n * 128 + kh * 64 + off;
            #pragma unroll
            for (int i = 0; i < 4; ++i)
                *(short8*)&sm.Ws[n][off + 8 * i] = *(const short8*)(wsrc + 8 * i);
        }
        __syncthreads();
        #pragma unroll
        for (int kc = 0; kc < 64; kc += 32) {
            short8 af = *(const short8*)&sm.Xs[wid * 16 + m][kc + q * 8];
            #pragma unroll
            for (int tde = 0; tde < 8; ++tde) {
                short8 bf = *(const short8*)&sm.Ws[tde * 16 + m][kc + q * 8];
                acc[tde] = __builtin_amdgcn_mfma_f32_16x16x32_bf16(af, bf, acc[tde], 0, 0, 0);
            }
        }
        __syncthreads();
    }
    #pragma unroll
    for (int r = 0; r < 4; ++r) {
        int grow = row0 + wid * 16 + q * 4 + r;
        if (grow < N) {
            float dn = dis[grow];   // coalesced/broadcast; folds D^-1/2 into h
            #pragma unroll
            for (int tde = 0; tde < 8; ++tde)
                h[(size_t)grow * 128 + tde * 16 + m] = f2bf(dn * acc[tde][r]);
        }
    }
}

// ---- gather: R17 loop on h' — no per-edge dis load (65.5us measured) ----
__global__ __launch_bounds__(256) void k_gather(const unsigned int* __restrict__ hb,
                                                const float* __restrict__ dis,
                                                const int* __restrict__ rowptr,
                                                const long* __restrict__ spackl,
                                                const float* __restrict__ bias,
                                                float* __restrict__ out, int N) {
    int gid = blockIdx.x * blockDim.x + threadIdx.x;
    int node = gid >> 6;
    int lane = gid & 63;
    if (node >= N) return;
    node = __builtin_amdgcn_readfirstlane(node);

    float dn = dis[node];
    unsigned u = hb[(size_t)node * 64 + lane];   // h'[node] = dn*h[node]
    float2 acc;
    acc.x = bf_lo(u);
    acc.y = bf_hi(u);

    int jb = rowptr[node], je = rowptr[node + 1];
    int j = jb;
    for (; j + 8 <= je; j += 8) {   // 8 h'-rows in flight
        long q0 = __builtin_nontemporal_load(spackl + j);
        long q1 = __builtin_nontemporal_load(spackl + j + 1);
        long q2 = __builtin_nontemporal_load(spackl + j + 2);
        long q3 = __builtin_nontemporal_load(spackl + j + 3);
        long q4 = __builtin_nontemporal_load(spackl + j + 4);
        long q5 = __builtin_nontemporal_load(spackl + j + 5);
        long q6 = __builtin_nontemporal_load(spackl + j + 6);
        long q7 = __builtin_nontemporal_load(spackl + j + 7);
        int r0 = __builtin_amdgcn_readfirstlane((int)q0);
        int r1 = __builtin_amdgcn_readfirstlane((int)q1);
        int r2 = __builtin_amdgcn_readfirstlane((int)q2);
        int r3 = __builtin_amdgcn_readfirstlane((int)q3);
        int r4 = __builtin_amdgcn_readfirstlane((int)q4);
        int r5 = __builtin_amdgcn_readfirstlane((int)q5);
        int r6 = __builtin_amdgcn_readfirstlane((int)q6);
        int r7 = __builtin_amdgcn_readfirstlane((int)q7);
        unsigned u0 = hb[(size_t)r0 * 64 + lane];
        unsigned u1 = hb[(size_t)r1 * 64 + lane];
        unsigned u2 = hb[(size_t)r2 * 64 + lane];
        unsigned u3 = hb[(size_t)r3 * 64 + lane];
        unsigned u4 = hb[(size_t)r4 * 64 + lane];
        unsigned u5 = hb[(size_t)r5 * 64 + lane];
        unsigned u6 = hb[(size_t)r6 * 64 + lane];
        unsigned u7 = hb[(size_t)r7 * 64 + lane];
        float a0 = __uint_as_float((unsigned)((unsigned long)q0 >> 32));
        float a1 = __uint_as_float((unsigned)((unsigned long)q1 >> 32));
        float a2 = __uint_as_float((unsigned)((unsigned long)q2 >> 32));
        float a3 = __uint_as_float((unsigned)((unsigned long)q3 >> 32));
        float a4 = __uint_as_float((unsigned)((unsigned long)q4 >> 32));
        float a5 = __uint_as_float((unsigned)((unsigned long)q5 >> 32));
        float a6 = __uint_as_float((unsigned)((unsigned long)q6 >> 32));
        float a7 = __uint_as_float((unsigned)((unsigned long)q7 >> 32));
        acc.x = fmaf(a0, bf_lo(u0), acc.x); acc.y = fmaf(a0, bf_hi(u0), acc.y);
        acc.x = fmaf(a1, bf_lo(u1), acc.x); acc.y = fmaf(a1, bf_hi(u1), acc.y);
        acc.x = fmaf(a2, bf_lo(u2), acc.x); acc.y = fmaf(a2, bf_hi(u2), acc.y);
        acc.x = fmaf(a3, bf_lo(u3), acc.x); acc.y = fmaf(a3, bf_hi(u3), acc.y);
        acc.x = fmaf(a4, bf_lo(u4), acc.x); acc.y = fmaf(a4, bf_hi(u4), acc.y);
        acc.x = fmaf(a5, bf_lo(u5), acc.x); acc.y = fmaf(a5, bf_hi(u5), acc.y);
        acc.x = fmaf(a6, bf_lo(u6), acc.x); acc.y = fmaf(a6, bf_hi(u6), acc.y);
        acc.x = fmaf(a7, bf_lo(u7), acc.x); acc.y = fmaf(a7, bf_hi(u7), acc.y);
    }
    for (; j < je; ++j) {
        long q = __builtin_nontemporal_load(spackl + j);
        int r = __builtin_amdgcn_readfirstlane((int)q);
        unsigned uu = hb[(size_t)r * 64 + lane];
        float a = __uint_as_float((unsigned)((unsigned long)q >> 32));
        acc.x = fmaf(a, bf_lo(uu), acc.x);
        acc.y = fmaf(a, bf_hi(uu), acc.y);
    }

    int c0 = lane * 2;
    float2 bv = *(const float2*)(bias + c0);
    float2 o;
    o.x = bv.x + dn * acc.x;
    o.y = bv.y + dn * acc.y;
    union { float2 f; double d; } cvt;
    cvt.f = o;
    __builtin_nontemporal_store(cvt.d, (double*)(out + (size_t)node * 128 + c0));
}

extern "C" void kernel_launch(void* const* d_in, const int* in_sizes, int n_in,
                              void* d_out, int out_size, void* d_ws, size_t ws_size,
                              hipStream_t stream) {
    const float* x     = (const float*)d_in[0];
    const int*   eidx  = (const int*)d_in[1];   // [2,E] int32
    const float* eattr = (const float*)d_in[2];
    const float* W     = (const float*)d_in[3];
    const float* bias  = (const float*)d_in[4];
    int N = in_sizes[0] / 128;
    int E = in_sizes[2];
    const int* row = eidx;
    const int* col = eidx + E;

    int NC = (N + 127) >> 7;                       // 782 buckets of 128 nodes
    int NBLK = (E + CHUNK - 1) / CHUNK;            // 782 place blocks

    char* p = (char*)d_ws;
    auto carve = [&](size_t bytes) {
        char* q = p;
        p += (bytes + 255) & ~(size_t)255;
        return q;
    };
    unsigned short* h   = (unsigned short*)carve((size_t)N * 128 * sizeof(unsigned short));
    unsigned short* Wtg = (unsigned short*)carve(128 * 128 * sizeof(unsigned short));
    float* dis    = (float*)carve((size_t)N * sizeof(float));
    int*   rowptr = (int*)carve((size_t)(N + 1) * sizeof(int));
    int2*  srw    = (int2*)carve(((size_t)NC * CAP + CAP) * sizeof(int2));  // +slack
    int2*  spack  = (int2*)carve((size_t)E * sizeof(int2));
    int*   gcur   = (int*)carve((size_t)NCMAX * sizeof(int));
    int*   bstart = (int*)carve((size_t)NCMAX * sizeof(int));

    int GB = (N + 63) / 64;   // 1563 gemm blocks

    hipMemsetAsync(gcur, 0, (size_t)NCMAX * sizeof(int), stream);
    k_place<<<NBLK, 256, 0, stream>>>(row, col, eattr, W, Wtg, gcur, srw, E, NC);
    k_bscan<<<1, 256, 0, stream>>>(gcur, bstart, NC);
    k_fine<<<NC, 256, 0, stream>>>(gcur, bstart, srw, rowptr, dis, spack, E, N, NC);
    k_gemm<<<GB, 256, 0, stream>>>(x, Wtg, dis, h, N);
    {
        size_t threads = (size_t)N * 64;
        int blocks = (int)((threads + 255) / 256);
        k_gather<<<blocks, 256, 0, stream>>>((const unsigned int*)h, dis, rowptr,
                                             (const long*)spack, bias, (float*)d_out, N);
    }
}

// Round 15
// 259.695 us; speedup vs baseline: 1.1198x; 1.1198x over previous
//
#include <hip/hip_runtime.h>

// GCNConv: out = D^-1/2 (A+I) D^-1/2 X W + b
// N=100000, E=1600000, Din=Dout=128; x/W/b fp32, edge_index int32, out fp32.
//
// R19 = R17 (248.9us) + histogram-matrix transpose fix:
//   histg's bucket-major layout made hist WRITE and place READ a column
//   (611K line-RMWs each way ~ 39MB effective traffic for 2.4MB data).
//   - hist writes block-major histB[blk][b]  (coalesced 3.2KB/block)
//   - k_tr : histB -> histT (bucket-major) via LDS 64x65 tiles (~2us)
//   - scan1/scan2 on histT (unchanged code)
//   - k_tr2: scanned histT + boff -> scanB (block-major, boff folded)
//   - place: reads count row + offset row COALESCED; pass A (LDS
//     re-count of 2048 edges) DELETED - counts already in histB.
//   fine/gemm(dis-fold)/gather byte-identical to R17.
//   R18 lesson locked in: no returning global atomics on hot counters.

#define ELEMS_PER_SCAN_BLOCK 4096  // 256 threads * 16
#define SCAN_SHIFT 12
#define CHUNK 2048                 // edges per hist/place block
#define NCP 800                    // padded bucket count >= NC=782

typedef __attribute__((ext_vector_type(8))) short short8;
typedef __attribute__((ext_vector_type(4))) float f32x4;

__device__ inline unsigned short f2bf(float f) {  // fp32 -> bf16 RNE
    unsigned u = __float_as_uint(f);
    u += 0x7fffu + ((u >> 16) & 1u);
    return (unsigned short)(u >> 16);
}
__device__ inline float bf_lo(unsigned u) { return __uint_as_float(u << 16); }
__device__ inline float bf_hi(unsigned u) { return __uint_as_float(u & 0xffff0000u); }

__device__ inline int wave_incl_scan(int x, int lane) {
    #pragma unroll
    for (int d = 1; d < 64; d <<= 1) {
        int y = __shfl_up(x, d, 64);
        if (lane >= d) x += y;
    }
    return x;
}

// ---- hist: block-major coalesced write + W-prep fold ----
__global__ __launch_bounds__(256) void k_hist(const int* __restrict__ col,
                                              const float* __restrict__ W,
                                              int* __restrict__ histB,
                                              unsigned short* __restrict__ Wtg,
                                              int E, int NBLK) {
    __shared__ int lh[1024];
    int t = threadIdx.x, blk = blockIdx.x;
    if (blk < 64) {  // W transpose+bf16: 2 rows per block
        int n = blk * 2 + (t >> 7);
        int k = t & 127;
        Wtg[n * 128 + k] = f2bf(W[k * 128 + n]);
    }
    for (int i = t; i < 1024; i += 256) lh[i] = 0;
    __syncthreads();
    int base = blk * CHUNK;
    #pragma unroll
    for (int i = 0; i < CHUNK / 256; ++i) {
        int e = base + i * 256 + t;
        if (e < E) atomicAdd(&lh[col[e] >> 7], 1);
    }
    __syncthreads();
    for (int b = t; b < NCP; b += 256) histB[blk * NCP + b] = lh[b];  // coalesced
}

// ---- tr: histB[blk][b] -> histT[b*NBLK+blk] (bucket-major for scan) ----
__global__ __launch_bounds__(256) void k_tr(const int* __restrict__ histB,
                                            int* __restrict__ histT,
                                            int NC, int NBLK, int TX) {
    __shared__ int tl[64][65];
    int t = threadIdx.x;
    int ti = blockIdx.x % TX;        // blk tile
    int tj = blockIdx.x / TX;        // bucket tile
    int k0 = ti * 64, b0 = tj * 64;
    for (int i = t; i < 4096; i += 256) {
        int r = i >> 6, c = i & 63;              // r: blk off, c: bucket off
        int gb = k0 + r, bb = b0 + c;
        tl[r][c] = (gb < NBLK && bb < NCP) ? histB[gb * NCP + bb] : 0;
    }
    __syncthreads();
    for (int i = t; i < 4096; i += 256) {
        int r = i >> 6, c = i & 63;              // r: bucket off, c: blk off
        int bb = b0 + r, gb = k0 + c;
        if (bb < NC && gb < NBLK) histT[bb * NBLK + gb] = tl[c][r];
    }
}

// ---- scans (pure, R17 form) ----
__global__ void k_scan1(const int* __restrict__ in, int* __restrict__ out,
                        int* __restrict__ bsum, int M) {
    __shared__ int wsum[4];
    __shared__ int woff[4];
    int t = threadIdx.x, lane = t & 63, wid = t >> 6;
    int base = blockIdx.x * ELEMS_PER_SCAN_BLOCK + t * 16;
    int v[16];
    #pragma unroll
    for (int i = 0; i < 16; ++i) v[i] = (base + i < M) ? in[base + i] : 0;
    int run = 0;
    #pragma unroll
    for (int i = 0; i < 16; ++i) { int x = v[i]; v[i] = run; run += x; }
    int incl = wave_incl_scan(run, lane);
    int excl = incl - run;
    if (lane == 63) wsum[wid] = incl;
    __syncthreads();
    if (t == 0) {
        int r = 0;
        #pragma unroll
        for (int w = 0; w < 4; ++w) { int s = wsum[w]; woff[w] = r; r += s; }
        bsum[blockIdx.x] = r;
    }
    __syncthreads();
    int off = woff[wid] + excl;
    #pragma unroll
    for (int i = 0; i < 16; ++i)
        if (base + i < M) out[base + i] = v[i] + off;
}

__global__ void k_scan2(const int* __restrict__ bsum, int* __restrict__ boff, int NB) {
    __shared__ int wsum[4];
    __shared__ int woff[4];
    int t = threadIdx.x, lane = t & 63, wid = t >> 6;
    int x = (t < NB) ? bsum[t] : 0;
    int incl = wave_incl_scan(x, lane);
    int excl = incl - x;
    if (lane == 63) wsum[wid] = incl;
    __syncthreads();
    if (t == 0) {
        int r = 0;
        #pragma unroll
        for (int w = 0; w < 4; ++w) { int s = wsum[w]; woff[w] = r; r += s; }
    }
    __syncthreads();
    if (t < NB) boff[t] = woff[wid] + excl;
}

// ---- tr2: scanned histT + boff -> scanB[blk][b] (block-major) ----
__global__ __launch_bounds__(256) void k_tr2(const int* __restrict__ histT,
                                             const int* __restrict__ boff,
                                             int* __restrict__ scanB,
                                             int NC, int NBLK, int TX) {
    __shared__ int tl[64][65];
    int t = threadIdx.x;
    int ti = blockIdx.x % TX;        // blk tile
    int tj = blockIdx.x / TX;        // bucket tile
    int k0 = ti * 64, b0 = tj * 64;
    for (int i = t; i < 4096; i += 256) {
        int r = i >> 6, c = i & 63;              // r: bucket off, c: blk off
        int bb = b0 + r, gb = k0 + c;
        int v = 0;
        if (bb < NC && gb < NBLK) {
            int g = bb * NBLK + gb;
            v = histT[g] + boff[g >> SCAN_SHIFT];
        }
        tl[r][c] = v;
    }
    __syncthreads();
    for (int i = t; i < 4096; i += 256) {
        int r = i >> 6, c = i & 63;              // r: blk off, c: bucket off
        int gb = k0 + r, bb = b0 + c;
        if (gb < NBLK && bb < NCP) scanB[gb * NCP + bb] = tl[c][r];
    }
}

// ---- place: counts/offsets read coalesced; pass A deleted ----
__global__ __launch_bounds__(256) void k_place(const int* __restrict__ row,
                                               const int* __restrict__ col,
                                               const float* __restrict__ wgt,
                                               const int* __restrict__ histB,
                                               const int* __restrict__ scanB,
                                               int2* __restrict__ srw,
                                               int E, int NC) {
    __shared__ struct { int lcnt[NCP]; int gadj[NCP]; int2 stage[CHUNK];
                        int sdst[CHUNK]; int wsum[4]; int woff[4]; } sp;  // 30.0 KB
    int t = threadIdx.x, blk = blockIdx.x;
    int lane = t & 63, wid = t >> 6;
    int base = blk * CHUNK;
    int nE = min(CHUNK, E - base);
    // counts row (coalesced); local exclusive scan
    int c4[4], cv[4];
    int sum = 0;
    #pragma unroll
    for (int i = 0; i < 4; ++i) {
        int idx = t * 4 + i;
        int v = histB[blk * NCP + idx];          // idx < NCP always (t*4+3 <= 1023; NCP=800 -> guard)
        if (idx >= NCP) v = 0;
        cv[i] = v;
        c4[i] = sum; sum += v;
    }
    int incl = wave_incl_scan(sum, lane);
    int excl = incl - sum;
    if (lane == 63) sp.wsum[wid] = incl;
    __syncthreads();
    if (t == 0) {
        int r = 0;
        #pragma unroll
        for (int w = 0; w < 4; ++w) { int s = sp.wsum[w]; sp.woff[w] = r; r += s; }
    }
    __syncthreads();
    int tb = sp.woff[wid] + excl;
    #pragma unroll
    for (int i = 0; i < 4; ++i) {
        int idx = t * 4 + i;
        if (idx < NCP) {
            int b0 = tb + c4[i];
            int gb = (idx < NC) ? scanB[blk * NCP + idx] : 0;   // coalesced
            sp.gadj[idx] = gb - b0;
            sp.lcnt[idx] = b0;
        }
    }
    __syncthreads();
    // scatter into LDS by bucket
    #pragma unroll
    for (int i = 0; i < CHUNK / 256; ++i) {
        int e = base + i * 256 + t;
        if (e < E) {
            int c = col[e];
            int slot = atomicAdd(&sp.lcnt[c >> 7], 1);
            sp.stage[slot] = make_int2(((c & 127) << 17) | row[e], __float_as_int(wgt[e]));
            sp.sdst[slot] = sp.gadj[c >> 7] + slot;
        }
    }
    __syncthreads();
    for (int s_ = t; s_ < nE; s_ += 256) {
        srw[sp.sdst[s_]] = sp.stage[s_];
    }
}

// ---- fine: exact CSR within each 128-node bucket + dis + spack (R17) ----
__global__ __launch_bounds__(256) void k_fine(const int* __restrict__ histT,
                                              const int* __restrict__ boff,
                                              const int2* __restrict__ srw,
                                              int* __restrict__ rowptr,
                                              float* __restrict__ dis,
                                              int2* __restrict__ spack,
                                              int E, int N, int NC, int NBLK) {
    __shared__ struct { int2 sbuf[3072]; int cnt128[128]; float degf[128];
                        int cur128[128]; int wtot[2]; } sf;   // 25.7 KB
    int t = threadIdx.x, b = blockIdx.x;
    int nb = b << 7;
    int g0 = b * NBLK;
    int start = histT[g0] + boff[g0 >> SCAN_SHIFT];
    int end;
    if (b == NC - 1) end = E;
    else {
        int g1 = (b + 1) * NBLK;
        end = histT[g1] + boff[g1 >> SCAN_SHIFT];
    }
    int cnt = end - start;
    int NL = min(cnt, 3072);
    if (t < 128) { sf.cnt128[t] = 0; sf.degf[t] = 1.0f; }  // 1.0 = self-loop
    __syncthreads();
    for (int j = t; j < cnt; j += 256) {
        int2 s = srw[start + j];
        if (j < NL) sf.sbuf[j] = s;
        int c = s.x >> 17;
        atomicAdd(&sf.cnt128[c], 1);
        atomicAdd(&sf.degf[c], __int_as_float(s.y));
    }
    __syncthreads();
    int v = 0, incl = 0;
    if (t < 128) {
        v = sf.cnt128[t];
        incl = wave_incl_scan(v, t & 63);
        if ((t & 63) == 63) sf.wtot[t >> 6] = incl;
    }
    __syncthreads();
    if (t < 128) {
        int excl = incl - v + ((t >= 64) ? sf.wtot[0] : 0);
        int p = start + excl;
        sf.cur128[t] = p;
        int n = nb + t;
        if (n < N) {
            rowptr[n] = p;
            dis[n] = rsqrtf(sf.degf[t]);
        }
    }
    if (t == 0 && b == NC - 1) rowptr[N] = E;
    __syncthreads();
    for (int j = t; j < cnt; j += 256) {
        int2 s = (j < NL) ? sf.sbuf[j] : srw[start + j];
        int c = s.x >> 17;
        int pos = atomicAdd(&sf.cur128[c], 1);
        spack[pos] = make_int2(s.x & 0x1FFFF, s.y);
    }
}

// ---- gemm: h' = (x @ W) scaled by dis (runs AFTER fine; R17) ----
__global__ __launch_bounds__(256) void k_gemm(const float* __restrict__ x,
                                              const unsigned short* __restrict__ Wtg,
                                              const float* __restrict__ dis,
                                              unsigned short* __restrict__ h, int N) {
    __shared__ struct { short Xs[64][72]; short Ws[128][72]; } sm;  // 27.6 KB
    int t = threadIdx.x;
    int lane = t & 63, wid = t >> 6;
    int row0 = blockIdx.x * 64;
    int q = lane >> 4;
    int m = lane & 15;
    f32x4 acc[8];
    #pragma unroll
    for (int tde = 0; tde < 8; ++tde) acc[tde] = (f32x4){0.f, 0.f, 0.f, 0.f};

    #pragma unroll
    for (int kh = 0; kh < 2; ++kh) {
        {   // X half: 64 rows x 64 K; 16 floats/thread
            int r = t >> 2;
            int kf = (t & 3) * 16;
            int gr = row0 + r;
            const float4* src = (const float4*)(x + (size_t)gr * 128 + kh * 64 + kf);
            float4 a0 = make_float4(0.f, 0.f, 0.f, 0.f), a1 = a0, a2 = a0, a3 = a0;
            if (gr < N) { a0 = src[0]; a1 = src[1]; a2 = src[2]; a3 = src[3]; }
            short8 p0, p1;
            p0[0] = (short)f2bf(a0.x); p0[1] = (short)f2bf(a0.y);
            p0[2] = (short)f2bf(a0.z); p0[3] = (short)f2bf(a0.w);
            p0[4] = (short)f2bf(a1.x); p0[5] = (short)f2bf(a1.y);
            p0[6] = (short)f2bf(a1.z); p0[7] = (short)f2bf(a1.w);
            p1[0] = (short)f2bf(a2.x); p1[1] = (short)f2bf(a2.y);
            p1[2] = (short)f2bf(a2.z); p1[3] = (short)f2bf(a2.w);
            p1[4] = (short)f2bf(a3.x); p1[5] = (short)f2bf(a3.y);
            p1[6] = (short)f2bf(a3.z); p1[7] = (short)f2bf(a3.w);
            *(short8*)&sm.Xs[r][kf]     = p0;
            *(short8*)&sm.Xs[r][kf + 8] = p1;
        }
        {   // W half: 128 rows x 64 K; 32 shorts/thread
            int n = t >> 1;
            int off = (t & 1) * 32;
            const short* wsrc = (const short*)Wtg + n * 128 + kh * 64 + off;
            #pragma unroll
            for (int i = 0; i < 4; ++i)
                *(short8*)&sm.Ws[n][off + 8 * i] = *(const short8*)(wsrc + 8 * i);
        }
        __syncthreads();
        #pragma unroll
        for (int kc = 0; kc < 64; kc += 32) {
            short8 af = *(const short8*)&sm.Xs[wid * 16 + m][kc + q * 8];
            #pragma unroll
            for (int tde = 0; tde < 8; ++tde) {
                short8 bf = *(const short8*)&sm.Ws[tde * 16 + m][kc + q * 8];
                acc[tde] = __builtin_amdgcn_mfma_f32_16x16x32_bf16(af, bf, acc[tde], 0, 0, 0);
            }
        }
        __syncthreads();
    }
    #pragma unroll
    for (int r = 0; r < 4; ++r) {
        int grow = row0 + wid * 16 + q * 4 + r;
        if (grow < N) {
            float dn = dis[grow];   // coalesced/broadcast; folds D^-1/2 into h
            #pragma unroll
            for (int tde = 0; tde < 8; ++tde)
                h[(size_t)grow * 128 + tde * 16 + m] = f2bf(dn * acc[tde][r]);
        }
    }
}

// ---- gather: R17 loop on h' — no per-edge dis load (65.5us measured) ----
__global__ __launch_bounds__(256) void k_gather(const unsigned int* __restrict__ hb,
                                                const float* __restrict__ dis,
                                                const int* __restrict__ rowptr,
                                                const long* __restrict__ spackl,
                                                const float* __restrict__ bias,
                                                float* __restrict__ out, int N) {
    int gid = blockIdx.x * blockDim.x + threadIdx.x;
    int node = gid >> 6;
    int lane = gid & 63;
    if (node >= N) return;
    node = __builtin_amdgcn_readfirstlane(node);

    float dn = dis[node];
    unsigned u = hb[(size_t)node * 64 + lane];   // h'[node] = dn*h[node]
    float2 acc;
    acc.x = bf_lo(u);
    acc.y = bf_hi(u);

    int jb = rowptr[node], je = rowptr[node + 1];
    int j = jb;
    for (; j + 8 <= je; j += 8) {   // 8 h'-rows in flight
        long q0 = __builtin_nontemporal_load(spackl + j);
        long q1 = __builtin_nontemporal_load(spackl + j + 1);
        long q2 = __builtin_nontemporal_load(spackl + j + 2);
        long q3 = __builtin_nontemporal_load(spackl + j + 3);
        long q4 = __builtin_nontemporal_load(spackl + j + 4);
        long q5 = __builtin_nontemporal_load(spackl + j + 5);
        long q6 = __builtin_nontemporal_load(spackl + j + 6);
        long q7 = __builtin_nontemporal_load(spackl + j + 7);
        int r0 = __builtin_amdgcn_readfirstlane((int)q0);
        int r1 = __builtin_amdgcn_readfirstlane((int)q1);
        int r2 = __builtin_amdgcn_readfirstlane((int)q2);
        int r3 = __builtin_amdgcn_readfirstlane((int)q3);
        int r4 = __builtin_amdgcn_readfirstlane((int)q4);
        int r5 = __builtin_amdgcn_readfirstlane((int)q5);
        int r6 = __builtin_amdgcn_readfirstlane((int)q6);
        int r7 = __builtin_amdgcn_readfirstlane((int)q7);
        unsigned u0 = hb[(size_t)r0 * 64 + lane];
        unsigned u1 = hb[(size_t)r1 * 64 + lane];
        unsigned u2 = hb[(size_t)r2 * 64 + lane];
        unsigned u3 = hb[(size_t)r3 * 64 + lane];
        unsigned u4 = hb[(size_t)r4 * 64 + lane];
        unsigned u5 = hb[(size_t)r5 * 64 + lane];
        unsigned u6 = hb[(size_t)r6 * 64 + lane];
        unsigned u7 = hb[(size_t)r7 * 64 + lane];
        float a0 = __uint_as_float((unsigned)((unsigned long)q0 >> 32));
        float a1 = __uint_as_float((unsigned)((unsigned long)q1 >> 32));
        float a2 = __uint_as_float((unsigned)((unsigned long)q2 >> 32));
        float a3 = __uint_as_float((unsigned)((unsigned long)q3 >> 32));
        float a4 = __uint_as_float((unsigned)((unsigned long)q4 >> 32));
        float a5 = __uint_as_float((unsigned)((unsigned long)q5 >> 32));
        float a6 = __uint_as_float((unsigned)((unsigned long)q6 >> 32));
        float a7 = __uint_as_float((unsigned)((unsigned long)q7 >> 32));
        acc.x = fmaf(a0, bf_lo(u0), acc.x); acc.y = fmaf(a0, bf_hi(u0), acc.y);
        acc.x = fmaf(a1, bf_lo(u1), acc.x); acc.y = fmaf(a1, bf_hi(u1), acc.y);
        acc.x = fmaf(a2, bf_lo(u2), acc.x); acc.y = fmaf(a2, bf_hi(u2), acc.y);
        acc.x = fmaf(a3, bf_lo(u3), acc.x); acc.y = fmaf(a3, bf_hi(u3), acc.y);
        acc.x = fmaf(a4, bf_lo(u4), acc.x); acc.y = fmaf(a4, bf_hi(u4), acc.y);
        acc.x = fmaf(a5, bf_lo(u5), acc.x); acc.y = fmaf(a5, bf_hi(u5), acc.y);
        acc.x = fmaf(a6, bf_lo(u6), acc.x); acc.y = fmaf(a6, bf_hi(u6), acc.y);
        acc.x = fmaf(a7, bf_lo(u7), acc.x); acc.y = fmaf(a7, bf_hi(u7), acc.y);
    }
    for (; j < je; ++j) {
        long q = __builtin_nontemporal_load(spackl + j);
        int r = __builtin_amdgcn_readfirstlane((int)q);
        unsigned uu = hb[(size_t)r * 64 + lane];
        float a = __uint_as_float((unsigned)((unsigned long)q >> 32));
        acc.x = fmaf(a, bf_lo(uu), acc.x);
        acc.y = fmaf(a, bf_hi(uu), acc.y);
    }

    int c0 = lane * 2;
    float2 bv = *(const float2*)(bias + c0);
    float2 o;
    o.x = bv.x + dn * acc.x;
    o.y = bv.y + dn * acc.y;
    union { float2 f; double d; } cvt;
    cvt.f = o;
    __builtin_nontemporal_store(cvt.d, (double*)(out + (size_t)node * 128 + c0));
}

extern "C" void kernel_launch(void* const* d_in, const int* in_sizes, int n_in,
                              void* d_out, int out_size, void* d_ws, size_t ws_size,
                              hipStream_t stream) {
    const float* x     = (const float*)d_in[0];
    const int*   eidx  = (const int*)d_in[1];   // [2,E] int32
    const float* eattr = (const float*)d_in[2];
    const float* W     = (const float*)d_in[3];
    const float* bias  = (const float*)d_in[4];
    int N = in_sizes[0] / 128;
    int E = in_sizes[2];
    const int* row = eidx;
    const int* col = eidx + E;

    int NC = (N + 127) >> 7;                       // 782 buckets of 128 nodes
    int NBLK = (E + CHUNK - 1) / CHUNK;            // 782 hist/place blocks

    char* p = (char*)d_ws;
    auto carve = [&](size_t bytes) {
        char* q = p;
        p += (bytes + 255) & ~(size_t)255;
        return q;
    };
    unsigned short* h   = (unsigned short*)carve((size_t)N * 128 * sizeof(unsigned short));
    unsigned short* Wtg = (unsigned short*)carve(128 * 128 * sizeof(unsigned short));
    float* dis    = (float*)carve((size_t)N * sizeof(float));
    int*   rowptr = (int*)carve((size_t)(N + 1) * sizeof(int));
    int*   histB  = (int*)carve((size_t)NBLK * NCP * sizeof(int));
    int*   histT  = (int*)carve((size_t)NC * NBLK * sizeof(int));
    int*   scanB  = (int*)carve((size_t)NBLK * NCP * sizeof(int));
    int2*  srw    = (int2*)carve((size_t)E * sizeof(int2));
    int2*  spack  = (int2*)carve((size_t)E * sizeof(int2));
    int*   bsum   = (int*)carve(256 * sizeof(int));
    int*   boff   = (int*)carve(256 * sizeof(int));

    int M = NC * NBLK;
    int NBs = (M + ELEMS_PER_SCAN_BLOCK - 1) / ELEMS_PER_SCAN_BLOCK;  // 150 <= 256
    int GB = (N + 63) / 64;   // 1563 gemm blocks
    int TX = (NBLK + 63) / 64;                 // 13
    int TY = (NC + 63) / 64;                   // 13

    k_hist<<<NBLK, 256, 0, stream>>>(col, W, histB, Wtg, E, NBLK);
    k_tr<<<TX * TY, 256, 0, stream>>>(histB, histT, NC, NBLK, TX);
    k_scan1<<<NBs, 256, 0, stream>>>(histT, histT, bsum, M);
    k_scan2<<<1, 256, 0, stream>>>(bsum, boff, NBs);
    k_tr2<<<TX * TY, 256, 0, stream>>>(histT, boff, scanB, NC, NBLK, TX);
    k_place<<<NBLK, 256, 0, stream>>>(row, col, eattr, histB, scanB, srw, E, NC);
    k_fine<<<NC, 256, 0, stream>>>(histT, boff, srw, rowptr, dis, spack, E, N, NC, NBLK);
    k_gemm<<<GB, 256, 0, stream>>>(x, Wtg, dis, h, N);
    {
        size_t threads = (size_t)N * 64;
        int blocks = (int)((threads + 255) / 256);
        k_gather<<<blocks, 256, 0, stream>>>((const unsigned int*)h, dis, rowptr,
                                             (const long*)spack, bias, (float*)d_out, N);
    }
}